// Round 7
// baseline (210.299 us; speedup 1.0000x reference)
//
#include <hip/hip_runtime.h>
#include <math.h>

namespace {
constexpr int SG = 14;
constexpr int NCELLS = 4096 * SG * SG;       // 802816
constexpr int CPT = 64;                      // cells per tile (one wave, 1 cell/lane)
constexpr int NTILES = NCELLS / CPT;         // 12544
constexpr int GRID = 1280;                   // 5 persistent blocks/CU * 256 CU
constexpr int TILE_BYTES = CPT * 30 * 4;     // 7680 B per input per tile
constexpr float STEPF = 1.0f / 14.0f;
constexpr float EPSF = 1e-6f;
constexpr float L_COORD = 7.0f;
constexpr float L_NOOBJ = 0.2f;
constexpr float L_CLS = 1.5f;
constexpr float INV_N = 1.0f / 4096.0f;
constexpr float FOUR_OVER_PI2 = 4.0f / (float)(M_PI * M_PI);
constexpr float PI_OVER_2 = 1.57079632679489662f;
}

#define AS1 __attribute__((address_space(1)))
#define AS3 __attribute__((address_space(3)))

// async global->LDS: per-lane global src, wave-uniform LDS base (+lane*size)
__device__ __forceinline__ void gl_lds16(const void* g, void* l) {
  __builtin_amdgcn_global_load_lds((const AS1 unsigned int*)g, (AS3 unsigned int*)l, 16, 0, 0);
}
__device__ __forceinline__ void gl_lds4(const void* g, void* l) {
  __builtin_amdgcn_global_load_lds((const AS1 unsigned int*)g, (AS3 unsigned int*)l, 4, 0, 0);
}

// 18 async vmem ops per call (7*2 x16B + 2*2 x4B) -> vmcnt bookkeeping below
__device__ __forceinline__ void stage_tile(const char* gp, const char* gt,
                                           char* lp, char* lt, int lane) {
#pragma unroll
  for (int j = 0; j < 7; ++j) {
    gl_lds16(gp + j * 1024 + lane * 16, lp + j * 1024);
    gl_lds16(gt + j * 1024 + lane * 16, lt + j * 1024);
  }
#pragma unroll
  for (int j = 0; j < 2; ++j) {
    gl_lds4(gp + 7168 + j * 256 + lane * 4, lp + 7168 + j * 256);
    gl_lds4(gt + 7168 + j * 256 + lane * 4, lt + 7168 + j * 256);
  }
}

struct Box { float x1, y1, x2, y2; };

__device__ __forceinline__ float iou_fn(const Box& a, const Box& b) {
  float ix1 = fmaxf(a.x1, b.x1);
  float iy1 = fmaxf(a.y1, b.y1);
  float ix2 = fminf(a.x2, b.x2);
  float iy2 = fminf(a.y2, b.y2);
  float inter = fmaxf(ix2 - ix1, 0.0f) * fmaxf(iy2 - iy1, 0.0f);
  float a1 = (a.x2 - a.x1) * (a.y2 - a.y1);
  float a2 = (b.x2 - b.x1) * (b.y2 - b.y1);
  return __fdividef(inter, a1 + a2 - inter + EPSF);
}

// atan(w/h) for w,h > 0: minimax odd poly on [0,1] + reflection. err ~1e-5 rad.
__device__ __forceinline__ float atan_ratio(float w, float h) {
  const float mn = fminf(w, h), mx = fmaxf(w, h);
  const float a = __fdividef(mn, mx);
  const float s = a * a;
  float r = -0.01172120f;
  r = r * s + 0.05265332f;
  r = r * s + -0.11643287f;
  r = r * s + 0.19354346f;
  r = r * s + -0.33262347f;
  r = r * s + 0.99997726f;
  r = r * a;
  return (w > h) ? (PI_OVER_2 - r) : r;
}

// BCE element; clip(log,-100) is lower-only. __logf(0) = -inf -> clamps to -100.
__device__ __forceinline__ float bce_term(float pc, float tc) {
  const float lg   = fmaxf(__logf(pc), -100.0f);
  const float l1mp = fmaxf(__logf(1.0f - pc), -100.0f);
  return -(tc * lg + (1.0f - tc) * l1mp);
}

// per-cell loss from LDS slabs (AoS record at lane*120 B)
__device__ __forceinline__ float cell_loss(const float* pbase, const float* tbase,
                                           int lane, int cell) {
  const float2* pl = reinterpret_cast<const float2*>(pbase + lane * 30);
  const float2* tl = reinterpret_cast<const float2*>(tbase + lane * 30);

  float p[10], t[10];
#pragma unroll
  for (int k = 0; k < 5; ++k) {
    const float2 v = pl[k]; p[2 * k] = v.x; p[2 * k + 1] = v.y;
    const float2 u = tl[k]; t[2 * k] = u.x; t[2 * k + 1] = u.y;
  }

  const int rem = cell % (SG * SG);
  const float gx = (float)(rem % SG);
  const float gy = (float)(rem / SG);

  Box pa0, pa1, ta0, ta1;
  {
    float cx = (p[0] + gx) * STEPF, cy = (p[1] + gy) * STEPF, w = p[2], h = p[3];
    pa0 = {cx - 0.5f * w, cy - 0.5f * h, cx + 0.5f * w, cy + 0.5f * h};
    cx = (p[5] + gx) * STEPF; cy = (p[6] + gy) * STEPF; w = p[7]; h = p[8];
    pa1 = {cx - 0.5f * w, cy - 0.5f * h, cx + 0.5f * w, cy + 0.5f * h};
    cx = (t[0] + gx) * STEPF; cy = (t[1] + gy) * STEPF; w = t[2]; h = t[3];
    ta0 = {cx - 0.5f * w, cy - 0.5f * h, cx + 0.5f * w, cy + 0.5f * h};
    cx = (t[5] + gx) * STEPF; cy = (t[6] + gy) * STEPF; w = t[7]; h = t[8];
    ta1 = {cx - 0.5f * w, cy - 0.5f * h, cx + 0.5f * w, cy + 0.5f * h};
  }

  // responsibility: both pred boxes vs TARGET BOX 0; argmax first-wins
  const float iou0 = iou_fn(pa0, ta0);
  const float iou1 = iou_fn(pa1, ta0);
  const bool m1 = iou1 > iou0;
  const bool obj0 = (t[4] > 0.0f) && !m1;
  const bool obj1 = (t[9] > 0.0f) && m1;
  const bool sig = obj0 || obj1;

  const float d0 = p[4] - t[4], d1 = p[9] - t[9];
  const float se0 = d0 * d0, se1 = d1 * d1;
  const float obj_loss   = (obj0 ? se0 : 0.0f) + (obj1 ? se1 : 0.0f);
  const float noobj_loss = (obj0 ? 0.0f : se0) + (obj1 ? 0.0f : se1);

  // CIoU for the responsible pairing (pred box mi vs target box mi)
  Box b1, b2;
  b1.x1 = m1 ? pa1.x1 : pa0.x1; b1.y1 = m1 ? pa1.y1 : pa0.y1;
  b1.x2 = m1 ? pa1.x2 : pa0.x2; b1.y2 = m1 ? pa1.y2 : pa0.y2;
  b2.x1 = m1 ? ta1.x1 : ta0.x1; b2.y1 = m1 ? ta1.y1 : ta0.y1;
  b2.x2 = m1 ? ta1.x2 : ta0.x2; b2.y2 = m1 ? ta1.y2 : ta0.y2;

  float bbox;
  {
    const float iou = iou_fn(b1, b2);
    const float cx1 = 0.5f * (b1.x1 + b1.x2), cy1 = 0.5f * (b1.y1 + b1.y2);
    const float cx2 = 0.5f * (b2.x1 + b2.x2), cy2 = 0.5f * (b2.y1 + b2.y2);
    const float cd = (cx1 - cx2) * (cx1 - cx2) + (cy1 - cy2) * (cy1 - cy2);
    const float ox1 = fminf(b1.x1, b2.x1), oy1 = fminf(b1.y1, b2.y1);
    const float ox2 = fmaxf(b1.x2, b2.x2), oy2 = fmaxf(b1.y2, b2.y2);
    const float od = (ox2 - ox1) * (ox2 - ox1) + (oy2 - oy1) * (oy2 - oy1) + EPSF;
    const float w1 = fmaxf(b1.x2 - b1.x1, EPSF), h1 = fmaxf(b1.y2 - b1.y1, EPSF);
    const float w2 = fmaxf(b2.x2 - b2.x1, EPSF), h2 = fmaxf(b2.y2 - b2.y1, EPSF);
    const float dat = atan_ratio(w2, h2) - atan_ratio(w1, h1);
    const float v = FOUR_OVER_PI2 * dat * dat;
    const float alpha = __fdividef(v, 1.0f - iou + v + EPSF);
    const float ciou = iou - __fdividef(cd, od) - alpha * v;
    const float scale = fmaxf(2.0f - w2 * h2, 1.0f);
    bbox = sig ? (1.0f - ciou) * scale : 0.0f;   // select AFTER: masks any NaN
  }

  // class BCE (20 classes) straight from LDS
  float cls = 0.0f;
#pragma unroll
  for (int k = 0; k < 10; ++k) {
    const float2 v = pl[5 + k];
    const float2 u = tl[5 + k];
    cls += bce_term(v.x, u.x) + bce_term(v.y, u.y);
  }

  return obj_loss + L_NOOBJ * noobj_loss + L_COORD * bbox
       + (sig ? L_CLS * cls : 0.0f);
}

__global__ __launch_bounds__(64) void yolo_k1(const float* __restrict__ pred,
                                              const float* __restrict__ tgt,
                                              float* __restrict__ bins) {
  // double-buffered staging: [buf][input][slab]  2*2*7680 = 30720 B -> 5 blocks/CU
  __shared__ __align__(16) float buf[2][2][CPT * 30];

  const int lane = threadIdx.x;
  const int bid = blockIdx.x;
  const char* pc = (const char*)pred;
  const char* tc = (const char*)tgt;

  float acc = 0.0f;
  int cur = 0;

  // prologue: stage first tile
  stage_tile(pc + (size_t)bid * TILE_BYTES, tc + (size_t)bid * TILE_BYTES,
             (char*)&buf[0][0][0], (char*)&buf[0][1][0], lane);

  for (int t = bid; t < NTILES; t += GRID) {
    const int tn = t + GRID;
    if (tn < NTILES) {
      // stage NEXT tile (18 more vmem ops), then wait only for CURRENT tile's 18
      stage_tile(pc + (size_t)tn * TILE_BYTES, tc + (size_t)tn * TILE_BYTES,
                 (char*)&buf[cur ^ 1][0][0], (char*)&buf[cur ^ 1][1][0], lane);
      asm volatile("s_waitcnt vmcnt(18)" ::: "memory");
    } else {
      asm volatile("s_waitcnt vmcnt(0)" ::: "memory");
    }
    // single-wave block: own gl_lds writes visible after waitcnt; no barrier.
    acc += cell_loss(&buf[cur][0][0], &buf[cur][1][0], lane, t * CPT + lane);
    cur ^= 1;
  }

  // wave64 reduce -> one atomic per block into a private bin
#pragma unroll
  for (int off = 32; off > 0; off >>= 1) acc += __shfl_down(acc, off);
  if (lane == 0) atomicAdd(&bins[bid], acc);
}

__global__ __launch_bounds__(256) void yolo_k2(const float* __restrict__ bins,
                                               float* __restrict__ out) {
  const int tid = threadIdx.x;
  float s = 0.0f;
#pragma unroll
  for (int i = 0; i < GRID / 256; ++i) s += bins[tid + 256 * i];
#pragma unroll
  for (int off = 32; off > 0; off >>= 1) s += __shfl_down(s, off);
  __shared__ float sd[4];
  if ((tid & 63) == 0) sd[tid >> 6] = s;
  __syncthreads();
  if (tid == 0) out[0] = (sd[0] + sd[1] + sd[2] + sd[3]) * INV_N;
}

extern "C" void kernel_launch(void* const* d_in, const int* in_sizes, int n_in,
                              void* d_out, int out_size, void* d_ws, size_t ws_size,
                              hipStream_t stream) {
  const float* pred = (const float*)d_in[0];
  const float* tgt  = (const float*)d_in[1];
  float* out  = (float*)d_out;
  float* bins = (float*)d_ws;            // GRID floats of scratch (poisoned each replay)

  hipMemsetAsync(bins, 0, GRID * sizeof(float), stream);
  yolo_k1<<<GRID, CPT, 0, stream>>>(pred, tgt, bins);
  yolo_k2<<<1, 256, 0, stream>>>(bins, out);   // overwrites out -> no out memset needed
}